// Round 5
// baseline (1203.946 us; speedup 1.0000x reference)
//
#include <hip/hip_runtime.h>
#include <hip/hip_bf16.h>

#define IGNORE_INDEX (-100)

typedef __bf16 bf16_t;
typedef __bf16 bf16x8 __attribute__((ext_vector_type(8)));
typedef float f32x4 __attribute__((ext_vector_type(4)));
typedef int i32x4 __attribute__((ext_vector_type(4)));

constexpr int NTOK = 4096;
constexpr int HID  = 2048;
constexpr int VOC  = 32000;
constexpr int BM = 128, BN = 128, BK = 32;
constexpr int NT_N = VOC / BN;   // 250 n-tiles
constexpr int NT_M = NTOK / BM;  // 32 m-tiles
constexpr int KT = HID / BK;     // 64 K-tiles

// ---- ws layout (bytes) ----
// Wbf  @ 0          : 32000*2048*2 = 131,072,000
// Xbf  @ 131072000  :  4096*2048*2 =  16,777,216
// pmax @ 147849216  :   250*4096*4 =   4,096,000   ([ntile][row])
// psum @ 151945216  :   250*4096*4 =   4,096,000
// xt   @ 156041216  :      4096*4
// loss @ 156057600  :      4096*4

__device__ __forceinline__ unsigned short f2bf(float f) {
  unsigned int x = __float_as_uint(f);
  return (unsigned short)((x + 0x7fffu + ((x >> 16) & 1u)) >> 16);  // RNE
}

__global__ void cvt_kernel(const float* __restrict__ src, unsigned short* __restrict__ dst, size_t n4) {
  size_t i = (size_t)blockIdx.x * blockDim.x + threadIdx.x;
  size_t stride = (size_t)gridDim.x * blockDim.x;
  const float4* s4 = reinterpret_cast<const float4*>(src);
  ushort4* d4 = reinterpret_cast<ushort4*>(dst);
  for (; i < n4; i += stride) {
    float4 a = s4[i];
    ushort4 o;
    o.x = f2bf(a.x); o.y = f2bf(a.y); o.z = f2bf(a.z); o.w = f2bf(a.w);
    d4[i] = o;
  }
}

// x_t[row] = dot(X[row], W[target[row]]) + bias[target[row]]   (fp32)
__global__ void xt_kernel(const float* __restrict__ X, const float* __restrict__ W,
                          const float* __restrict__ bias, const int* __restrict__ tgt,
                          float* __restrict__ xt) {
  int row = blockIdx.x * 4 + (threadIdx.x >> 6);
  int lane = threadIdx.x & 63;
  if (row >= NTOK) return;
  int t = tgt[row];
  if (t < 0 || t >= VOC) { if (lane == 0) xt[row] = 0.0f; return; }
  const float4* xr = reinterpret_cast<const float4*>(X + (size_t)row * HID);
  const float4* wr = reinterpret_cast<const float4*>(W + (size_t)t * HID);
  float s = 0.0f;
  for (int i = lane; i < HID / 4; i += 64) {
    float4 a = xr[i], b = wr[i];
    s += a.x * b.x + a.y * b.y + a.z * b.z + a.w * b.w;
  }
#pragma unroll
  for (int d = 1; d < 64; d <<= 1) s += __shfl_xor(s, d);
  if (lane == 0) xt[row] = s + bias[t];
}

// Fused bf16 GEMM (logits tile) + per-row (max, sumexp) partials.
// 128x128 tile, BK=32, 4 waves 2x2 (wave tile 64x64), 3 blocks/CU (TLP overlap).
// A (X rows, L2-hot) loaded DIRECT global->VGPR via inline asm, double-buffered
// one tile ahead. Only B staged in LDS: 4-slab ring, glds(t+3), R4's verified
// zero-conflict XOR swizzle. One barrier + one counted vmcnt per K-tile.
// vmcnt ledger (per body t, issue order G(t+3)^2, A(t+1)^4):
//   pre-MFMA(t) vmcnt(6) == |{G(t+3),A(t+1)}| newer than A(t)  => A(t) landed;
//   in-order retirement  => G(t) retired before barrier(t) in EVERY wave
//   (12+ newer ops at that wave's previous vmcnt(6)) => ds_read(t) race-free.
//   glds(t+3) writes slab (t-1)&3, issued after barrier(t), and all readers of
//   slab (t-1) finished before barrier(t) => write race-free.
__global__ __launch_bounds__(256, 3) void gemm_lse_kernel(
    const bf16_t* __restrict__ Xb, const bf16_t* __restrict__ Wb,
    const float* __restrict__ bias,
    float* __restrict__ pmax, float* __restrict__ psum) {
  __shared__ __align__(16) bf16_t Bs[4][BN * BK];  // 4 x 8 KB
  __shared__ float redM[2][BM];
  __shared__ float redS[2][BM];

  // XCD-chunked swizzle, mtile-fastest (8000 % 8 == 0, bijective)
  const int nwg = NT_M * NT_N;           // 8000
  const int xcd = blockIdx.x & 7;
  const int pos = blockIdx.x >> 3;
  const int wgid = xcd * (nwg >> 3) + pos;
  const int mtile = wgid & (NT_M - 1);   // 32 consecutive blocks share W panel
  const int ntile = wgid >> 5;
  const int mbase = mtile * BM;
  const int nbase = ntile * BN;

  const int tid = threadIdx.x;
  const int w = tid >> 6;                // 0..3
  const int lane = tid & 63;
  const int wm = w >> 1, wn = w & 1;     // wave -> 64x64 output sub-tile
  const int l15 = lane & 15;
  const int kgrp = lane >> 4;            // 0..3

  // ---- B staging: linear LDS dest, inverse-swizzled global source ----
  // thread tid, issue j: LDS elems [j*2048 + tid*8, +8) -> row = j*64+(tid>>2),
  // stored slot s = tid&3 holds global chunk c = s ^ ((row>>1)&3) = s ^ ((tid>>3)&3).
  const int srow = tid >> 2;                          // 0..63
  const int csrc = (tid & 3) ^ ((tid >> 3) & 3);
  const bf16_t* bSt0 = Wb + (size_t)(nbase + srow) * HID + csrc * 8;
  const bf16_t* bSt1 = bSt0 + (size_t)64 * HID;       // j=1: +64 rows

  // ds_read B: row r = wn*64 + ni*16 + l15; global chunk kgrp stored at
  // kgrp ^ ((r>>1)&3) = kgrp ^ ((l15>>1)&3)  (wn*64, ni*16 == 0 mod 8).
  const int swz = (kgrp ^ ((l15 >> 1) & 3)) * 8;
  const int brow0 = wn * 64 + l15;

  // ---- A direct: per-lane global addresses (X rows, mi = 0..3) ----
  const bf16_t* aP0 = Xb + (size_t)(mbase + wm * 64 +  0 + l15) * HID + kgrp * 8;
  const bf16_t* aP1 = Xb + (size_t)(mbase + wm * 64 + 16 + l15) * HID + kgrp * 8;
  const bf16_t* aP2 = Xb + (size_t)(mbase + wm * 64 + 32 + l15) * HID + kgrp * 8;
  const bf16_t* aP3 = Xb + (size_t)(mbase + wm * 64 + 48 + l15) * HID + kgrp * 8;

  f32x4 acc[4][4];
#pragma unroll
  for (int mi = 0; mi < 4; ++mi)
#pragma unroll
    for (int ni = 0; ni < 4; ++ni)
#pragma unroll
      for (int j = 0; j < 4; ++j) acc[mi][ni][j] = 0.0f;

  float bv[4];
#pragma unroll
  for (int ni = 0; ni < 4; ++ni) bv[ni] = bias[nbase + wn * 64 + ni * 16 + l15];

  i32x4 aC[4], aN[4];

#define GLDS(SRC, DST)                                                              \
  __builtin_amdgcn_global_load_lds((const __attribute__((address_space(1))) void*)(SRC), \
                                   (__attribute__((address_space(3))) void*)(DST), 16, 0, 0)
#define STAGE(tk)                                                                   \
  { int b_ = (tk) & 3;                                                              \
    GLDS(bSt0 + (size_t)(tk) * BK, &Bs[b_][tid * 8]);                               \
    GLDS(bSt1 + (size_t)(tk) * BK, &Bs[b_][tid * 8 + 2048]); }
#define ALOAD(dst, ptr)                                                             \
  asm volatile("global_load_dwordx4 %0, %1, off" : "=v"(dst) : "v"(ptr) : "memory")

  // BODY(t): bar | glds(t+3) | ds_read B(t) | A-load(t+1) | vmcnt | MFMA
#define BODY(T, AC, AN, DO_G, DO_A, VMSTR)                                          \
  {                                                                                 \
    asm volatile("" ::: "memory");                                                  \
    __builtin_amdgcn_s_barrier();                                                   \
    asm volatile("" ::: "memory");                                                  \
    if (DO_G) STAGE((T) + 3);                                                       \
    const bf16_t* Bb = &Bs[(T) & 3][0];                                             \
    bf16x8 bg[4];                                                                   \
    _Pragma("unroll")                                                               \
    for (int ni = 0; ni < 4; ++ni)                                                  \
      bg[ni] = *reinterpret_cast<const bf16x8*>(Bb + (brow0 + ni * 16) * BK + swz); \
    if (DO_A) {                                                                     \
      ALOAD(AN[0], aP0 + (size_t)((T) + 1) * BK);                                   \
      ALOAD(AN[1], aP1 + (size_t)((T) + 1) * BK);                                   \
      ALOAD(AN[2], aP2 + (size_t)((T) + 1) * BK);                                   \
      ALOAD(AN[3], aP3 + (size_t)((T) + 1) * BK);                                   \
    }                                                                               \
    asm volatile(VMSTR ::: "memory");                                               \
    __builtin_amdgcn_sched_barrier(0);                                              \
    __builtin_amdgcn_s_setprio(1);                                                  \
    _Pragma("unroll")                                                               \
    for (int mi = 0; mi < 4; ++mi) {                                                \
      bf16x8 af = __builtin_bit_cast(bf16x8, AC[mi]);                               \
      _Pragma("unroll")                                                             \
      for (int ni = 0; ni < 4; ++ni)                                                \
        acc[mi][ni] = __builtin_amdgcn_mfma_f32_16x16x32_bf16(af, bg[ni],           \
                                                              acc[mi][ni], 0, 0, 0);\
    }                                                                               \
    __builtin_amdgcn_s_setprio(0);                                                  \
    __builtin_amdgcn_sched_barrier(0);                                              \
  }

  // prologue: B slabs 0..2 (6 glds), A(0) (4 loads); retire G(0..2) pre-barrier
  STAGE(0); STAGE(1); STAGE(2);
  ALOAD(aC[0], aP0); ALOAD(aC[1], aP1); ALOAD(aC[2], aP2); ALOAD(aC[3], aP3);
  asm volatile("s_waitcnt vmcnt(8)" ::: "memory");  // 8 newer than G(2): A(0)4 only 4... G0,G1,G2 retired (10 issued, keep A(0)+4 margin)

  for (int t = 0; t < 60; t += 2) {
    BODY(t,     aC, aN, true, true, "s_waitcnt vmcnt(6)")
    BODY(t + 1, aN, aC, true, true, "s_waitcnt vmcnt(6)")
  }
  BODY(60, aC, aN, true,  true,  "s_waitcnt vmcnt(6)")
  BODY(61, aN, aC, false, true,  "s_waitcnt vmcnt(4)")
  BODY(62, aC, aN, false, true,  "s_waitcnt vmcnt(4)")
  BODY(63, aN, aC, false, false, "s_waitcnt vmcnt(0)")

#undef BODY
#undef ALOAD
#undef STAGE
#undef GLDS

  // ---- epilogue: per-row (max, sumexp) over this block's 128 cols ----
  // C frag: col = l15 (B row), row = kgrp*4 + j (A row) — verified R1-R4
#pragma unroll
  for (int mi = 0; mi < 4; ++mi) {
#pragma unroll
    for (int j = 0; j < 4; ++j) {
      float v0 = acc[mi][0][j] + bv[0];
      float v1 = acc[mi][1][j] + bv[1];
      float v2 = acc[mi][2][j] + bv[2];
      float v3 = acc[mi][3][j] + bv[3];
      float mx = fmaxf(fmaxf(v0, v1), fmaxf(v2, v3));
#pragma unroll
      for (int d = 1; d < 16; d <<= 1) mx = fmaxf(mx, __shfl_xor(mx, d));
      float s = __expf(v0 - mx) + __expf(v1 - mx) + __expf(v2 - mx) + __expf(v3 - mx);
#pragma unroll
      for (int d = 1; d < 16; d <<= 1) s += __shfl_xor(s, d);
      if (l15 == 0) {
        int lr = wm * 64 + mi * 16 + kgrp * 4 + j;
        redM[wn][lr] = mx;
        redS[wn][lr] = s;
      }
    }
  }
  __syncthreads();
  if (tid < BM) {
    float m0 = redM[0][tid], m1 = redM[1][tid];
    float M = fmaxf(m0, m1);
    float S = __expf(m0 - M) * redS[0][tid] + __expf(m1 - M) * redS[1][tid];
    size_t row = (size_t)mbase + tid;
    pmax[(size_t)ntile * NTOK + row] = M;   // coalesced over tid
    psum[(size_t)ntile * NTOK + row] = S;
  }
}

// merge 250 partials per row -> lse -> per-row loss
__global__ void lse_kernel(const float* __restrict__ pmax, const float* __restrict__ psum,
                           const float* __restrict__ xt, const int* __restrict__ tgt,
                           float* __restrict__ loss) {
  int row = blockIdx.x * 4 + (threadIdx.x >> 6);
  int lane = threadIdx.x & 63;
  if (row >= NTOK) return;
  float M = -3.4e38f;
  for (int i = lane; i < NT_N; i += 64) M = fmaxf(M, pmax[(size_t)i * NTOK + row]);
#pragma unroll
  for (int d = 1; d < 64; d <<= 1) M = fmaxf(M, __shfl_xor(M, d));
  float S = 0.0f;
  for (int i = lane; i < NT_N; i += 64)
    S += __expf(pmax[(size_t)i * NTOK + row] - M) * psum[(size_t)i * NTOK + row];
#pragma unroll
  for (int d = 1; d < 64; d <<= 1) S += __shfl_xor(S, d);
  if (lane == 0) {
    int tg = tgt[row];
    bool valid = (tg != IGNORE_INDEX);
    float lse = M + __logf(S);
    loss[row] = valid ? (lse - xt[row]) : 0.0f;
  }
}

__global__ void final_kernel(const float* __restrict__ loss, const int* __restrict__ tgt,
                             float* __restrict__ out) {
  __shared__ float shs[256];
  __shared__ float shc[256];
  int tid = threadIdx.x;
  float s = 0.0f, c = 0.0f;
  for (int i = tid; i < NTOK; i += 256) {
    s += loss[i];
    c += (tgt[i] != IGNORE_INDEX) ? 1.0f : 0.0f;
  }
  shs[tid] = s; shc[tid] = c;
  __syncthreads();
  for (int off = 128; off > 0; off >>= 1) {
    if (tid < off) { shs[tid] += shs[tid + off]; shc[tid] += shc[tid + off]; }
    __syncthreads();
  }
  if (tid == 0) out[0] = shs[0] / fmaxf(shc[0], 1.0f);
}

extern "C" void kernel_launch(void* const* d_in, const int* in_sizes, int n_in,
                              void* d_out, int out_size, void* d_ws, size_t ws_size,
                              hipStream_t stream) {
  const float* W    = (const float*)d_in[0];  // [32000][2048]
  const float* X    = (const float*)d_in[1];  // [4096][2048]
  const int*   tgt  = (const int*)d_in[2];    // [4096]
  const float* bias = (const float*)d_in[3];  // [32000]
  float* out = (float*)d_out;

  char* ws = (char*)d_ws;
  bf16_t* Wb   = (bf16_t*)(ws);
  bf16_t* Xb   = (bf16_t*)(ws + 131072000);
  float*  pmax = (float*) (ws + 147849216);
  float*  psum = (float*) (ws + 151945216);
  float*  xt   = (float*) (ws + 156041216);
  float*  loss = (float*) (ws + 156057600);

  cvt_kernel<<<2048, 256, 0, stream>>>(W, (unsigned short*)Wb, (size_t)VOC * HID / 4);
  cvt_kernel<<<512, 256, 0, stream>>>(X, (unsigned short*)Xb, (size_t)NTOK * HID / 4);
  xt_kernel<<<NTOK / 4, 256, 0, stream>>>(X, W, bias, tgt, xt);
  gemm_lse_kernel<<<NT_M * NT_N, 256, 0, stream>>>(Xb, Wb, bias, pmax, psum);
  lse_kernel<<<NTOK / 4, 256, 0, stream>>>(pmax, psum, xt, tgt, loss);
  final_kernel<<<1, 256, 0, stream>>>(loss, tgt, out);
}

// Round 6
// 786.083 us; speedup vs baseline: 1.5316x; 1.5316x over previous
//
#include <hip/hip_runtime.h>
#include <hip/hip_bf16.h>

#define IGNORE_INDEX (-100)

typedef __bf16 bf16_t;
typedef __bf16 bf16x8 __attribute__((ext_vector_type(8)));
typedef float f32x4 __attribute__((ext_vector_type(4)));

constexpr int NTOK = 4096;
constexpr int HID  = 2048;
constexpr int VOC  = 32000;
constexpr int BM = 128, BN = 128, BK = 32;
constexpr int NT_N = VOC / BN;   // 250 n-tiles
constexpr int NT_M = NTOK / BM;  // 32 m-tiles

// ---- ws layout (bytes) ----
// Wbf  @ 0          : 32000*2048*2 = 131,072,000
// Xbf  @ 131072000  :  4096*2048*2 =  16,777,216
// pmax @ 147849216  :   250*4096*4 =   4,096,000   ([ntile][row])
// psum @ 151945216  :   250*4096*4 =   4,096,000
// xt   @ 156041216  :      4096*4
// loss @ 156057600  :      4096*4

__device__ __forceinline__ unsigned short f2bf(float f) {
  unsigned int x = __float_as_uint(f);
  return (unsigned short)((x + 0x7fffu + ((x >> 16) & 1u)) >> 16);  // RNE
}

__global__ void cvt_kernel(const float* __restrict__ src, unsigned short* __restrict__ dst, size_t n4) {
  size_t i = (size_t)blockIdx.x * blockDim.x + threadIdx.x;
  size_t stride = (size_t)gridDim.x * blockDim.x;
  const float4* s4 = reinterpret_cast<const float4*>(src);
  ushort4* d4 = reinterpret_cast<ushort4*>(dst);
  for (; i < n4; i += stride) {
    float4 a = s4[i];
    ushort4 o;
    o.x = f2bf(a.x); o.y = f2bf(a.y); o.z = f2bf(a.z); o.w = f2bf(a.w);
    d4[i] = o;
  }
}

// x_t[row] = dot(X[row], W[target[row]]) + bias[target[row]]   (fp32)
__global__ void xt_kernel(const float* __restrict__ X, const float* __restrict__ W,
                          const float* __restrict__ bias, const int* __restrict__ tgt,
                          float* __restrict__ xt) {
  int row = blockIdx.x * 4 + (threadIdx.x >> 6);
  int lane = threadIdx.x & 63;
  if (row >= NTOK) return;
  int t = tgt[row];
  if (t < 0 || t >= VOC) { if (lane == 0) xt[row] = 0.0f; return; }
  const float4* xr = reinterpret_cast<const float4*>(X + (size_t)row * HID);
  const float4* wr = reinterpret_cast<const float4*>(W + (size_t)t * HID);
  float s = 0.0f;
  for (int i = lane; i < HID / 4; i += 64) {
    float4 a = xr[i], b = wr[i];
    s += a.x * b.x + a.y * b.y + a.z * b.z + a.w * b.w;
  }
#pragma unroll
  for (int d = 1; d < 64; d <<= 1) s += __shfl_xor(s, d);
  if (lane == 0) xt[row] = s + bias[t];
}

// Fused bf16 GEMM (logits tile) + per-row (max, sumexp) partials.
// m97 structure (measured 912 TF on gfx950): 128x128 tile, BK=32, 4 waves 2x2,
// single-buffered 16KB LDS, 2 __syncthreads per K-iter, global_load_lds w=16,
// compiler-scheduled waits. Overlap comes from 3 blocks/CU TLP (m114), pinned
// via __launch_bounds__(256,3).
// Fixes vs R1: (a) R4's MEASURED-zero-conflict swizzle (stored chunk =
// c ^ ((row>>1)&3), inverse on global src, linear LDS dest);
// (b) mtile-fastest + bijective XCD-chunked grid (FETCH 2.5GB -> ~0.7GB).
__global__ __launch_bounds__(256, 3) void gemm_lse_kernel(
    const bf16_t* __restrict__ Xb, const bf16_t* __restrict__ Wb,
    const float* __restrict__ bias,
    float* __restrict__ pmax, float* __restrict__ psum) {
  __shared__ __align__(16) bf16_t As[BM * BK];   // 8 KB
  __shared__ __align__(16) bf16_t Bs[BN * BK];   // 8 KB
  __shared__ float redM[2][BM];
  __shared__ float redS[2][BM];

  // XCD-chunked swizzle, mtile-fastest (8000 % 8 == 0, bijective)
  const int nwg = NT_M * NT_N;           // 8000
  const int xcd = blockIdx.x & 7;
  const int pos = blockIdx.x >> 3;
  const int wgid = xcd * (nwg >> 3) + pos;
  const int mtile = wgid & (NT_M - 1);   // 32 consecutive blocks share W panel
  const int ntile = wgid >> 5;
  const int mbase = mtile * BM;
  const int nbase = ntile * BN;

  const int tid = threadIdx.x;
  const int w = tid >> 6;                // 0..3
  const int lane = tid & 63;
  const int wr = w >> 1, wc = w & 1;     // wave -> 64x64 output sub-tile
  const int l15 = lane & 15;
  const int kgrp = lane >> 4;            // 0..3

  // ---- staging: linear LDS dest, inverse-swizzled global source ----
  // thread tid, issue j: LDS elems [j*2048 + tid*8, +8) -> row = j*64+(tid>>2),
  // stored slot s = tid&3 holds global chunk c = s ^ ((row>>1)&3) = s ^ ((tid>>3)&3).
  const int srow = tid >> 2;                          // 0..63
  const int csrc = (tid & 3) ^ ((tid >> 3) & 3);
  const bf16_t* aSt0 = Xb + (size_t)(mbase + srow) * HID + csrc * 8;
  const bf16_t* aSt1 = aSt0 + (size_t)64 * HID;       // j=1: +64 rows
  const bf16_t* bSt0 = Wb + (size_t)(nbase + srow) * HID + csrc * 8;
  const bf16_t* bSt1 = bSt0 + (size_t)64 * HID;

  // ds_read: row r, global chunk kgrp stored at kgrp ^ ((r>>1)&3);
  // (r>>1)&3 = (l15>>1)&3 for our rows (wr*64, wc*64, mi*16 all ≡ 0 mod 16).
  const int swz = (kgrp ^ ((l15 >> 1) & 3)) * 8;      // element offset in row
  const int arow0 = wr * 64 + l15;
  const int brow0 = wc * 64 + l15;

  f32x4 acc[4][4];
#pragma unroll
  for (int mi = 0; mi < 4; ++mi)
#pragma unroll
    for (int ni = 0; ni < 4; ++ni)
#pragma unroll
      for (int j = 0; j < 4; ++j) acc[mi][ni][j] = 0.0f;

  float bv[4];
#pragma unroll
  for (int ni = 0; ni < 4; ++ni) bv[ni] = bias[nbase + wc * 64 + ni * 16 + l15];

#define GLDS(SRC, DST)                                                              \
  __builtin_amdgcn_global_load_lds((const __attribute__((address_space(1))) void*)(SRC), \
                                   (__attribute__((address_space(3))) void*)(DST), 16, 0, 0)

  for (int k0 = 0; k0 < HID; k0 += BK) {
    __syncthreads();
    GLDS(aSt0 + k0, As + tid * 8);
    GLDS(aSt1 + k0, As + 2048 + tid * 8);
    GLDS(bSt0 + k0, Bs + tid * 8);
    GLDS(bSt1 + k0, Bs + 2048 + tid * 8);
    __syncthreads();

    bf16x8 af[4], bg[4];
#pragma unroll
    for (int mi = 0; mi < 4; ++mi)
      af[mi] = *reinterpret_cast<const bf16x8*>(As + (arow0 + mi * 16) * BK + swz);
#pragma unroll
    for (int ni = 0; ni < 4; ++ni)
      bg[ni] = *reinterpret_cast<const bf16x8*>(Bs + (brow0 + ni * 16) * BK + swz);
#pragma unroll
    for (int mi = 0; mi < 4; ++mi)
#pragma unroll
      for (int ni = 0; ni < 4; ++ni)
        acc[mi][ni] = __builtin_amdgcn_mfma_f32_16x16x32_bf16(af[mi], bg[ni], acc[mi][ni], 0, 0, 0);
  }
#undef GLDS

  // ---- epilogue: per-row (max, sumexp) over this block's 128 cols ----
  // C frag: col = l15 (B row), row = kgrp*4 + j (A row) — verified R1-R5
#pragma unroll
  for (int mi = 0; mi < 4; ++mi) {
#pragma unroll
    for (int j = 0; j < 4; ++j) {
      float v0 = acc[mi][0][j] + bv[0];
      float v1 = acc[mi][1][j] + bv[1];
      float v2 = acc[mi][2][j] + bv[2];
      float v3 = acc[mi][3][j] + bv[3];
      float mx = fmaxf(fmaxf(v0, v1), fmaxf(v2, v3));
#pragma unroll
      for (int d = 1; d < 16; d <<= 1) mx = fmaxf(mx, __shfl_xor(mx, d));
      float s = __expf(v0 - mx) + __expf(v1 - mx) + __expf(v2 - mx) + __expf(v3 - mx);
#pragma unroll
      for (int d = 1; d < 16; d <<= 1) s += __shfl_xor(s, d);
      if (l15 == 0) {
        int lr = wr * 64 + mi * 16 + kgrp * 4 + j;
        redM[wc][lr] = mx;
        redS[wc][lr] = s;
      }
    }
  }
  __syncthreads();
  if (tid < BM) {
    float m0 = redM[0][tid], m1 = redM[1][tid];
    float M = fmaxf(m0, m1);
    float S = __expf(m0 - M) * redS[0][tid] + __expf(m1 - M) * redS[1][tid];
    size_t row = (size_t)mbase + tid;
    pmax[(size_t)ntile * NTOK + row] = M;   // coalesced over tid
    psum[(size_t)ntile * NTOK + row] = S;
  }
}

// merge 250 partials per row -> lse -> per-row loss
__global__ void lse_kernel(const float* __restrict__ pmax, const float* __restrict__ psum,
                           const float* __restrict__ xt, const int* __restrict__ tgt,
                           float* __restrict__ loss) {
  int row = blockIdx.x * 4 + (threadIdx.x >> 6);
  int lane = threadIdx.x & 63;
  if (row >= NTOK) return;
  float M = -3.4e38f;
  for (int i = lane; i < NT_N; i += 64) M = fmaxf(M, pmax[(size_t)i * NTOK + row]);
#pragma unroll
  for (int d = 1; d < 64; d <<= 1) M = fmaxf(M, __shfl_xor(M, d));
  float S = 0.0f;
  for (int i = lane; i < NT_N; i += 64)
    S += __expf(pmax[(size_t)i * NTOK + row] - M) * psum[(size_t)i * NTOK + row];
#pragma unroll
  for (int d = 1; d < 64; d <<= 1) S += __shfl_xor(S, d);
  if (lane == 0) {
    int tg = tgt[row];
    bool valid = (tg != IGNORE_INDEX);
    float lse = M + __logf(S);
    loss[row] = valid ? (lse - xt[row]) : 0.0f;
  }
}

__global__ void final_kernel(const float* __restrict__ loss, const int* __restrict__ tgt,
                             float* __restrict__ out) {
  __shared__ float shs[256];
  __shared__ float shc[256];
  int tid = threadIdx.x;
  float s = 0.0f, c = 0.0f;
  for (int i = tid; i < NTOK; i += 256) {
    s += loss[i];
    c += (tgt[i] != IGNORE_INDEX) ? 1.0f : 0.0f;
  }
  shs[tid] = s; shc[tid] = c;
  __syncthreads();
  for (int off = 128; off > 0; off >>= 1) {
    if (tid < off) { shs[tid] += shs[tid + off]; shc[tid] += shc[tid + off]; }
    __syncthreads();
  }
  if (tid == 0) out[0] = shs[0] / fmaxf(shc[0], 1.0f);
}

extern "C" void kernel_launch(void* const* d_in, const int* in_sizes, int n_in,
                              void* d_out, int out_size, void* d_ws, size_t ws_size,
                              hipStream_t stream) {
  const float* W    = (const float*)d_in[0];  // [32000][2048]
  const float* X    = (const float*)d_in[1];  // [4096][2048]
  const int*   tgt  = (const int*)d_in[2];    // [4096]
  const float* bias = (const float*)d_in[3];  // [32000]
  float* out = (float*)d_out;

  char* ws = (char*)d_ws;
  bf16_t* Wb   = (bf16_t*)(ws);
  bf16_t* Xb   = (bf16_t*)(ws + 131072000);
  float*  pmax = (float*) (ws + 147849216);
  float*  psum = (float*) (ws + 151945216);
  float*  xt   = (float*) (ws + 156041216);
  float*  loss = (float*) (ws + 156057600);

  cvt_kernel<<<2048, 256, 0, stream>>>(W, (unsigned short*)Wb, (size_t)VOC * HID / 4);
  cvt_kernel<<<512, 256, 0, stream>>>(X, (unsigned short*)Xb, (size_t)NTOK * HID / 4);
  xt_kernel<<<NTOK / 4, 256, 0, stream>>>(X, W, bias, tgt, xt);
  gemm_lse_kernel<<<NT_M * NT_N, 256, 0, stream>>>(Xb, Wb, bias, pmax, psum);
  lse_kernel<<<NTOK / 4, 256, 0, stream>>>(pmax, psum, xt, tgt, loss);
  final_kernel<<<1, 256, 0, stream>>>(loss, tgt, out);
}